// Round 2
// baseline (226.330 us; speedup 1.0000x reference)
//
#include <hip/hip_runtime.h>

// out[b,c,l] = sum_{k=0..6} x[b,c,l+k-3] * w[b, c%G, k, l]   (zero-pad in l)
// B=8, C=256, L=8192, G=64, K=7  -> pure memory-bound (~240 MiB min traffic)

constexpr int Bn   = 8;
constexpr int Cn   = 256;
constexpr int Ln   = 8192;
constexpr int Gn   = 64;
constexpr int Kn   = 7;
constexpr int CPG  = Cn / Gn;          // 4 channels share one weight group
constexpr int LPT  = 4;                // l positions per thread (float4)
constexpr int BLOCK = 256;
constexpr int TILE_L = BLOCK * LPT;    // 1024 l positions per block
constexpr int NTILE  = Ln / TILE_L;    // 8

__global__ __launch_bounds__(BLOCK) void ska1d_kernel(
    const float* __restrict__ x,
    const float* __restrict__ w,
    float* __restrict__ out)
{
    const int bid   = blockIdx.x;
    const int ltile = bid % NTILE;
    const int g     = (bid / NTILE) % Gn;
    const int b     = bid / (NTILE * Gn);
    const int l0    = ltile * TILE_L + threadIdx.x * LPT;

    // ---- load w[b][g][k][l0..l0+3] for k=0..6, keep in registers ----
    const float* wbase = w + ((size_t)(b * Gn + g) * Kn) * Ln + l0;
    float wf[Kn][4];
#pragma unroll
    for (int k = 0; k < Kn; ++k) {
        float4 wv = *reinterpret_cast<const float4*>(wbase + (size_t)k * Ln);
        wf[k][0] = wv.x; wf[k][1] = wv.y; wf[k][2] = wv.z; wf[k][3] = wv.w;
    }

    // ---- for each of the 4 channels in this group ----
#pragma unroll
    for (int j = 0; j < CPG; ++j) {
        const int c = g + j * Gn;               // c % Gn == g
        const float* xrow = x + ((size_t)(b * Cn + c)) * Ln;

        // window x[l0-4 .. l0+7] via three aligned float4 loads (zero-pad edges)
        float4 va = (l0 >= 4)
                  ? *reinterpret_cast<const float4*>(xrow + l0 - 4)
                  : make_float4(0.f, 0.f, 0.f, 0.f);
        float4 vb = *reinterpret_cast<const float4*>(xrow + l0);
        float4 vc = (l0 + 4 < Ln)
                  ? *reinterpret_cast<const float4*>(xrow + l0 + 4)
                  : make_float4(0.f, 0.f, 0.f, 0.f);

        float xs[12];
        xs[0] = va.x; xs[1] = va.y; xs[2]  = va.z; xs[3]  = va.w;
        xs[4] = vb.x; xs[5] = vb.y; xs[6]  = vb.z; xs[7]  = vb.w;
        xs[8] = vc.x; xs[9] = vc.y; xs[10] = vc.z; xs[11] = vc.w;

        // out[l0+i] = sum_k x[l0+i+k-3] * w[k][l0+i] = sum_k xs[1+i+k] * wf[k][i]
        float4 o;
        float* op = &o.x;
#pragma unroll
        for (int i = 0; i < 4; ++i) {
            float acc = 0.f;
#pragma unroll
            for (int k = 0; k < Kn; ++k)
                acc = fmaf(xs[1 + i + k], wf[k][i], acc);
            op[i] = acc;
        }
        *reinterpret_cast<float4*>(out + ((size_t)(b * Cn + c)) * Ln + l0) = o;
    }
}

extern "C" void kernel_launch(void* const* d_in, const int* in_sizes, int n_in,
                              void* d_out, int out_size, void* d_ws, size_t ws_size,
                              hipStream_t stream)
{
    const float* x = (const float*)d_in[0];
    const float* w = (const float*)d_in[1];
    float* out     = (float*)d_out;

    const int grid = Bn * Gn * NTILE;   // 4096 blocks
    ska1d_kernel<<<grid, BLOCK, 0, stream>>>(x, w, out);
}

// Round 3
// 225.948 us; speedup vs baseline: 1.0017x; 1.0017x over previous
//
#include <hip/hip_runtime.h>

// out[b,c,l] = sum_{k=0..6} x[b,c,l+k-3] * w[b, c%G, k, l]   (zero-pad in l)
// B=8, C=256, L=8192, G=64, K=7. Memory-bound; fix = max per-wave MLP:
// issue ALL 19 float4 loads before any compute (sched_barrier fence).

constexpr int Bn   = 8;
constexpr int Cn   = 256;
constexpr int Ln   = 8192;
constexpr int Gn   = 64;
constexpr int Kn   = 7;
constexpr int CPG  = Cn / Gn;            // 4 channels share one weight group
constexpr int LPT  = 4;                  // l positions per thread (float4)
constexpr int BLOCK = 256;
constexpr int TILE_L = BLOCK * LPT;      // 1024
constexpr int NTILE  = Ln / TILE_L;      // 8
constexpr size_t CH_STRIDE = (size_t)Gn * Ln;   // channel c -> c+Gn (same group)

__global__ __launch_bounds__(BLOCK, 4) void ska1d_kernel(
    const float* __restrict__ x,
    const float* __restrict__ w,
    float* __restrict__ out)
{
    const int bid   = blockIdx.x;
    const int ltile = bid % NTILE;
    const int g     = (bid / NTILE) % Gn;
    const int b     = bid / (NTILE * Gn);
    const int l0    = ltile * TILE_L + (int)threadIdx.x * LPT;

    const float* wp = w   + ((size_t)(b * Gn + g) * Kn) * Ln + l0;
    const float* xp = x   + ((size_t)b * Cn + g) * Ln + l0;
    float*       op = out + ((size_t)b * Cn + g) * Ln + l0;

    const bool has_lo = (l0 >= 4);
    const bool has_hi = (l0 + LPT < Ln);
    const float4 z = make_float4(0.f, 0.f, 0.f, 0.f);

    // ---- issue ALL loads first; results stay live in VGPRs ----
    float4 W[Kn];
#pragma unroll
    for (int k = 0; k < Kn; ++k)
        W[k] = *reinterpret_cast<const float4*>(wp + (size_t)k * Ln);

    float4 A[CPG], Bv[CPG], Cv[CPG];
#pragma unroll
    for (int j = 0; j < CPG; ++j) {
        const float* xj = xp + j * CH_STRIDE;
        A[j]  = has_lo ? *reinterpret_cast<const float4*>(xj - 4) : z;
        Bv[j] = *reinterpret_cast<const float4*>(xj);
        Cv[j] = has_hi ? *reinterpret_cast<const float4*>(xj + 4) : z;
    }

    // fence: no compute may be hoisted above, no load may sink below
    __builtin_amdgcn_sched_barrier(0);

    // ---- compute + store ----
#pragma unroll
    for (int j = 0; j < CPG; ++j) {
        float xs[12];
        xs[0] = A[j].x;  xs[1] = A[j].y;  xs[2]  = A[j].z;  xs[3]  = A[j].w;
        xs[4] = Bv[j].x; xs[5] = Bv[j].y; xs[6]  = Bv[j].z; xs[7]  = Bv[j].w;
        xs[8] = Cv[j].x; xs[9] = Cv[j].y; xs[10] = Cv[j].z; xs[11] = Cv[j].w;

        float4 o;
        float* opx = &o.x;
        const float* Wf = &W[0].x;   // W[k] component i  ==  Wf[k*4+i]
#pragma unroll
        for (int i = 0; i < 4; ++i) {
            float acc = 0.f;
#pragma unroll
            for (int k = 0; k < Kn; ++k)
                acc = fmaf(xs[1 + i + k], Wf[k * 4 + i], acc);
            opx[i] = acc;
        }
        *reinterpret_cast<float4*>(op + j * CH_STRIDE) = o;
    }
}

extern "C" void kernel_launch(void* const* d_in, const int* in_sizes, int n_in,
                              void* d_out, int out_size, void* d_ws, size_t ws_size,
                              hipStream_t stream)
{
    const float* x = (const float*)d_in[0];
    const float* w = (const float*)d_in[1];
    float* out     = (float*)d_out;

    const int grid = Bn * Gn * NTILE;   // 4096 blocks
    ska1d_kernel<<<grid, BLOCK, 0, stream>>>(x, w, out);
}